// Round 1
// baseline (311.682 us; speedup 1.0000x reference)
//
#include <hip/hip_runtime.h>
#include <hip/hip_fp16.h>

#define NN 100000
#define NE 1600000
#define FIN 128
#define HD 64
#define CO 40
#define NG 2048
#define NSB 196           // super-buckets of 512 nodes: ceil(100000/512)
#define SCAP 9216         // super-bucket capacity (mean 8163, +11 sigma)
#define GCAP 13312        // padded ssrc capacity per group (SCAP + 512*7 pad)
#define CHUNK 4096        // edges per scatter block
#define NSCAT ((NE + CHUNK - 1) / CHUNK)   // 391

// ---------------- setup: cursors + zero readout + zero dummy hws row ----------------
__global__ __launch_bounds__(256) void setup_kernel(int* __restrict__ scur,
                                                    float* __restrict__ readout,
                                                    unsigned int* __restrict__ dummy) {
    int gid = blockIdx.x * 256 + threadIdx.x;
    if (gid < NG * HD) readout[gid] = 0.0f;
    if (gid < NSB) scur[gid * 16] = gid * SCAP;
    if (gid < HD / 2) dummy[gid] = 0u;   // 64 halves = 32 uints
}

// =====================================================================
// P1: binned scatter into 196 super-buckets (512 nodes each).
// 1024 threads/block (R13: was 256 -> 1.5 waves/SIMD; now 6/SIMD) and
// (dst,src) cached in registers across the two phases (saves re-read).
// =====================================================================
__global__ __launch_bounds__(1024) void scatter_super(const int* __restrict__ src,
                                                      const int* __restrict__ dst,
                                                      int* __restrict__ scur,
                                                      unsigned int* __restrict__ stmp) {
    __shared__ int hist[NSB];
    __shared__ int gbase[NSB];
    int tid = threadIdx.x;
    int e0 = blockIdx.x * CHUNK;
    int d[4], s[4];
    if (tid < NSB) hist[tid] = 0;
    __syncthreads();
#pragma unroll
    for (int r = 0; r < 4; r++) {
        int e = e0 + tid + r * 1024;
        d[r] = -1; s[r] = 0;
        if (e < NE) {
            d[r] = dst[e];
            s[r] = src[e];
            atomicAdd(&hist[d[r] >> 9], 1);
        }
    }
    __syncthreads();
    if (tid < NSB) {
        int c = hist[tid];
        gbase[tid] = (c > 0) ? atomicAdd(&scur[tid * 16], c) : 0;
        hist[tid] = 0;
    }
    __syncthreads();
#pragma unroll
    for (int r = 0; r < 4; r++) {
        if (d[r] >= 0) {
            int b = d[r] >> 9;
            int p = atomicAdd(&hist[b], 1);
            stmp[gbase[b] + p] = ((unsigned int)(d[r] & 511) << 17) | (unsigned int)s[r];
        }
    }
}

// =====================================================================
// P2: per-super-bucket counting sort (512 node bins) -> padded ssrc,
// offs/degn/di. 1024 threads/block (R13: was 256; 196 blocks were the
// occupancy floor of the pipeline). Edges cached in 9 regs across the
// histogram -> scatter phases: stmp is read ONCE.
// =====================================================================
__global__ __launch_bounds__(1024) void group_sort(const int* __restrict__ scur,
                                                   const unsigned int* __restrict__ stmp,
                                                   unsigned int* __restrict__ ssrc,
                                                   int* __restrict__ offs,
                                                   int* __restrict__ degn,
                                                   float* __restrict__ di) {
    __shared__ int lh[512];
    __shared__ int sc[512];
    __shared__ int lcur[512];
    int g = blockIdx.x;
    int tid = threadIdx.x;
    int base = g * SCAP;
    int cnt = scur[g * 16] - base;
    if (tid < 512) lh[tid] = 0;
    __syncthreads();
    unsigned int uv[9];          // SCAP/1024 == 9 exactly
#pragma unroll
    for (int r = 0; r < 9; r++) {
        int i = tid + r * 1024;
        uv[r] = 0xFFFFFFFFu;     // valid entries are < 2^26, sentinel safe
        if (i < cnt) {
            uv[r] = stmp[base + i];
            atomicAdd(&lh[uv[r] >> 17], 1);
        }
    }
    __syncthreads();
    int h = 0, pd = 0;
    if (tid < 512) {
        h = lh[tid];
        pd = (h + 7) & ~7;
        sc[tid] = pd;
    }
    __syncthreads();
    for (int off = 1; off < 512; off <<= 1) {
        int v = 0;
        if (tid >= off && tid < 512) v = sc[tid - off];
        __syncthreads();
        if (tid < 512) sc[tid] += v;
        __syncthreads();
    }
    if (tid < 512) {
        int excl = sc[tid] - pd;    // exclusive scan of padded counts
        lcur[tid] = excl;
        int node = g * 512 + tid;
        if (node < NN) {
            offs[node] = g * GCAP + excl;
            degn[node] = pd;
            di[node] = rsqrtf((float)h + 1.0f);
        }
        size_t gb = (size_t)g * GCAP;
        for (int q = h; q < pd; q++) ssrc[gb + excl + q] = (unsigned int)NN;  // pads -> zero row
    }
    __syncthreads();
#pragma unroll
    for (int r = 0; r < 9; r++) {
        unsigned int u = uv[r];
        if (u != 0xFFFFFFFFu) {
            int dl = (int)(u >> 17);
            int pos = atomicAdd(&lcur[dl], 1);
            ssrc[(size_t)g * GCAP + pos] = u & 0x1FFFFu;
        }
    }
}

// ---------------- W_eff = pre_w @ c1_w ; b_eff = pre_b @ c1_w (one-shot) ----------------
__global__ __launch_bounds__(256) void weff_kernel(const float* __restrict__ pre_w,
                                                   const float* __restrict__ pre_b,
                                                   const float* __restrict__ c1_w,
                                                   float* __restrict__ weff,
                                                   float* __restrict__ beff) {
    if (blockIdx.x < 32) {
        int o = blockIdx.x * 256 + threadIdx.x;
        int r = o >> 6, c = o & 63;
        float acc = 0.0f;
#pragma unroll 8
        for (int k = 0; k < HD; k++) acc = fmaf(pre_w[r * HD + k], c1_w[k * HD + c], acc);
        weff[o] = acc;
    } else {
        int c = threadIdx.x;
        if (c < HD) {
            float acc = 0.0f;
#pragma unroll 8
            for (int k = 0; k < HD; k++) acc = fmaf(pre_b[k], c1_w[k * HD + c], acc);
            beff[c] = acc;
        }
    }
}

// =====================================================================
// Tiled GEMM 1: hws = half((x @ W_eff + b_eff) * di)   [N,128]@[128,64]
// =====================================================================
__global__ __launch_bounds__(256) void gemm1_tiled(const float* __restrict__ x,
                                                   const float* __restrict__ w,
                                                   const float* __restrict__ b,
                                                   const float* __restrict__ di,
                                                   __half* __restrict__ hws) {
    __shared__ float wS[FIN * HD];   // 32 KB
    __shared__ float xS[64 * 64];    // 16 KB (one K-half)
    int tid = threadIdx.x;
    for (int i = tid; i < FIN * HD; i += 256) wS[i] = w[i];
    int tn = tid & 15, tf = tid >> 4;
    int f0 = tf * 4;
    float4 bv = ((const float4*)b)[tf];
    int ntiles = (NN + 63) >> 6;
    for (int t = blockIdx.x; t < ntiles; t += gridDim.x) {
        int nb = t << 6;
        float acc[4][4];
#pragma unroll
        for (int i = 0; i < 4; i++)
#pragma unroll
            for (int j = 0; j < 4; j++) acc[i][j] = 0.0f;
        for (int kh = 0; kh < 2; kh++) {
            __syncthreads();
            {
                int n_l = tid >> 4;
                int k4l = tid & 15;
                for (int r = 0; r < 4; r++) {
                    int n = n_l + r * 16;
                    int row = nb + n;
                    float4 v = make_float4(0.f, 0.f, 0.f, 0.f);
                    if (row < NN) v = ((const float4*)(x + (size_t)row * FIN))[kh * 16 + k4l];
                    int g = n >> 2, nl2 = n & 3;
                    const float* vp = (const float*)&v;
#pragma unroll
                    for (int j = 0; j < 4; j++) {
                        int k = k4l * 4 + j;
                        int gp = g ^ (k & 15);
                        xS[k * 64 + gp * 4 + nl2] = vp[j];
                    }
                }
            }
            __syncthreads();
#pragma unroll 4
            for (int kl = 0; kl < 64; kl++) {
                int gp = tn ^ (kl & 15);
                float4 xv = *(const float4*)&xS[kl * 64 + gp * 4];
                float4 wv = *(const float4*)&wS[(kh * 64 + kl) * 64 + f0];
                acc[0][0] = fmaf(xv.x, wv.x, acc[0][0]); acc[0][1] = fmaf(xv.x, wv.y, acc[0][1]);
                acc[0][2] = fmaf(xv.x, wv.z, acc[0][2]); acc[0][3] = fmaf(xv.x, wv.w, acc[0][3]);
                acc[1][0] = fmaf(xv.y, wv.x, acc[1][0]); acc[1][1] = fmaf(xv.y, wv.y, acc[1][1]);
                acc[1][2] = fmaf(xv.y, wv.z, acc[1][2]); acc[1][3] = fmaf(xv.y, wv.w, acc[1][3]);
                acc[2][0] = fmaf(xv.z, wv.x, acc[2][0]); acc[2][1] = fmaf(xv.z, wv.y, acc[2][1]);
                acc[2][2] = fmaf(xv.z, wv.z, acc[2][2]); acc[2][3] = fmaf(xv.z, wv.w, acc[2][3]);
                acc[3][0] = fmaf(xv.w, wv.x, acc[3][0]); acc[3][1] = fmaf(xv.w, wv.y, acc[3][1]);
                acc[3][2] = fmaf(xv.w, wv.z, acc[3][2]); acc[3][3] = fmaf(xv.w, wv.w, acc[3][3]);
            }
        }
        int n0 = nb + tn * 4;
#pragma unroll
        for (int i = 0; i < 4; i++) {
            int n = n0 + i;
            if (n < NN) {
                float dn = di[n];
                __half2 p0 = __floats2half2_rn((acc[i][0] + bv.x) * dn, (acc[i][1] + bv.y) * dn);
                __half2 p1 = __floats2half2_rn((acc[i][2] + bv.z) * dn, (acc[i][3] + bv.w) * dn);
                __half2* o = (__half2*)(hws + (size_t)n * HD + f0);
                o[0] = p0; o[1] = p1;
            }
        }
    }
}

// =====================================================================
// Tiled GEMM 2: hws = half((h1 @ c2_w) * di)   [N,64]@[64,64], h1 fp16
// =====================================================================
__global__ __launch_bounds__(256) void conv_gemm_tiled(const __half* __restrict__ hin,
                                                       const float* __restrict__ w,
                                                       const float* __restrict__ di,
                                                       __half* __restrict__ hws) {
    __shared__ float wS[HD * HD];
    __shared__ float xS[64 * HD];
    int tid = threadIdx.x;
    for (int i = tid; i < HD * HD; i += 256) wS[i] = w[i];
    int tn = tid & 15, tf = tid >> 4;
    int f0 = tf * 4;
    int ntiles = (NN + 63) >> 6;
    for (int t = blockIdx.x; t < ntiles; t += gridDim.x) {
        int nb = t << 6;
        __syncthreads();
        {
            int n_l = tid >> 3;
            int k8 = tid & 7;
            union U { float4 f4; __half2 h2[4]; } u;
            for (int r = 0; r < 2; r++) {
                int n = n_l + r * 32;
                int row = nb + n;
                u.f4 = make_float4(0.f, 0.f, 0.f, 0.f);
                if (row < NN) u.f4 = ((const float4*)(hin + (size_t)row * HD))[k8];
                int g = n >> 2, nl2 = n & 3;
#pragma unroll
                for (int j = 0; j < 4; j++) {
                    float2 p = __half22float2(u.h2[j]);
                    int k = k8 * 8 + 2 * j;
                    int gp = g ^ (k & 15);
                    xS[k * 64 + gp * 4 + nl2] = p.x;
                    int k2 = k + 1;
                    int gp2 = g ^ (k2 & 15);
                    xS[k2 * 64 + gp2 * 4 + nl2] = p.y;
                }
            }
        }
        __syncthreads();
        float acc[4][4];
#pragma unroll
        for (int i = 0; i < 4; i++)
#pragma unroll
            for (int j = 0; j < 4; j++) acc[i][j] = 0.0f;
#pragma unroll 4
        for (int k = 0; k < HD; k++) {
            int gp = tn ^ (k & 15);
            float4 xv = *(const float4*)&xS[k * 64 + gp * 4];
            float4 wv = *(const float4*)&wS[k * 64 + f0];
            acc[0][0] = fmaf(xv.x, wv.x, acc[0][0]); acc[0][1] = fmaf(xv.x, wv.y, acc[0][1]);
            acc[0][2] = fmaf(xv.x, wv.z, acc[0][2]); acc[0][3] = fmaf(xv.x, wv.w, acc[0][3]);
            acc[1][0] = fmaf(xv.y, wv.x, acc[1][0]); acc[1][1] = fmaf(xv.y, wv.y, acc[1][1]);
            acc[1][2] = fmaf(xv.y, wv.z, acc[1][2]); acc[1][3] = fmaf(xv.y, wv.w, acc[1][3]);
            acc[2][0] = fmaf(xv.z, wv.x, acc[2][0]); acc[2][1] = fmaf(xv.z, wv.y, acc[2][1]);
            acc[2][2] = fmaf(xv.z, wv.z, acc[2][2]); acc[2][3] = fmaf(xv.z, wv.w, acc[2][3]);
            acc[3][0] = fmaf(xv.w, wv.x, acc[3][0]); acc[3][1] = fmaf(xv.w, wv.y, acc[3][1]);
            acc[3][2] = fmaf(xv.w, wv.z, acc[3][2]); acc[3][3] = fmaf(xv.w, wv.w, acc[3][3]);
        }
        int n0 = nb + tn * 4;
#pragma unroll
        for (int i = 0; i < 4; i++) {
            int n = n0 + i;
            if (n < NN) {
                float dn = di[n];
                __half2 p0 = __floats2half2_rn(acc[i][0] * dn, acc[i][1] * dn);
                __half2 p1 = __floats2half2_rn(acc[i][2] * dn, acc[i][3] * dn);
                __half2* o = (__half2*)(hws + (size_t)n * HD + f0);
                o[0] = p0; o[1] = p1;
            }
        }
    }
}

// =====================================================================
// R13 gather core: ONE NODE PER 8-LANE GROUP (8 nodes/wave).
// Lane (g=lane>>3, fp=lane&7) owns features [fp*8, fp*8+8) of node g.
// No shuffle-broadcast of indices (group-uniform uint4 loads, L1 bcast),
// no cross-rsub reduce epilogue (accumulator is feature-resident).
// Precision parity with the old 8-way scheme: 4 interleaved half2
// accumulator sets (chain ~deg/4), combined in fp32.
// pdeg is a multiple of 8; pads read the zeroed dummy row NN.
// =====================================================================
__device__ __forceinline__ void gather_node8(const int* __restrict__ offs,
                                             const int* __restrict__ pdeg,
                                             const unsigned int* __restrict__ ssrc,
                                             const __half* __restrict__ hws,
                                             int node, int fp, float acc[8]) {
    int i0 = offs[node];
    int deg = pdeg[node];                    // multiple of 8 (may be 0)
    union U { float4 f4; __half2 h2[4]; } u[8];
    __half2 hacc[4][4];
#pragma unroll
    for (int s = 0; s < 4; s++)
#pragma unroll
        for (int t = 0; t < 4; t++) hacc[s][t] = __floats2half2_rn(0.f, 0.f);
    // self-loop row
    u[0].f4 = ((const float4*)(hws + (size_t)node * HD))[fp];
#pragma unroll
    for (int t = 0; t < 4; t++) hacc[0][t] = u[0].h2[t];
    const uint4* ip = (const uint4*)(ssrc + i0);     // 16B-aligned (offs multiple of 8)
    if (deg > 0) {
        uint4 sa = ip[0], sb = ip[1];
        for (int j = 0; j < deg; j += 8) {
            // prefetch next iteration's indices (induction-based, breaks the
            // idx->addr->load serial chain; clamped re-read on last iter)
            int nxt = (j + 8 < deg) ? (j >> 2) + 2 : 0;
            uint4 na = ip[nxt], nb = ip[nxt + 1];
            u[0].f4 = ((const float4*)(hws + (size_t)sa.x * HD))[fp];
            u[1].f4 = ((const float4*)(hws + (size_t)sa.y * HD))[fp];
            u[2].f4 = ((const float4*)(hws + (size_t)sa.z * HD))[fp];
            u[3].f4 = ((const float4*)(hws + (size_t)sa.w * HD))[fp];
            u[4].f4 = ((const float4*)(hws + (size_t)sb.x * HD))[fp];
            u[5].f4 = ((const float4*)(hws + (size_t)sb.y * HD))[fp];
            u[6].f4 = ((const float4*)(hws + (size_t)sb.z * HD))[fp];
            u[7].f4 = ((const float4*)(hws + (size_t)sb.w * HD))[fp];
#pragma unroll
            for (int q = 0; q < 8; q++)
#pragma unroll
                for (int t = 0; t < 4; t++)
                    hacc[q & 3][t] = __hadd2(hacc[q & 3][t], u[q].h2[t]);
            sa = na; sb = nb;
        }
    }
    // combine the 4 half2 sets in fp32
#pragma unroll
    for (int t = 0; t < 4; t++) {
        float2 a = __half22float2(hacc[0][t]);
        float2 b = __half22float2(hacc[1][t]);
        float2 c = __half22float2(hacc[2][t]);
        float2 d = __half22float2(hacc[3][t]);
        acc[2 * t]     = (a.x + b.x) + (c.x + d.x);
        acc[2 * t + 1] = (a.y + b.y) + (c.y + d.y);
    }
}

// LN over the 8-features-per-lane layout; xor 1,2,4 stays inside the
// 8-lane group (lane bits 0..2 == fp). Returns relu'd y[8].
__device__ __forceinline__ void ln8(float v[8], int fp,
                                    const float* __restrict__ g,
                                    const float* __restrict__ bb,
                                    float y[8]) {
    float su = 0.0f;
#pragma unroll
    for (int t = 0; t < 8; t++) su += v[t];
    su += __shfl_xor(su, 1, 64); su += __shfl_xor(su, 2, 64); su += __shfl_xor(su, 4, 64);
    float mu = su * (1.0f / HD);
    float q = 0.0f;
#pragma unroll
    for (int t = 0; t < 8; t++) { float d = v[t] - mu; q += d * d; }
    q += __shfl_xor(q, 1, 64); q += __shfl_xor(q, 2, 64); q += __shfl_xor(q, 4, 64);
    float rstd = rsqrtf(q * (1.0f / HD) + 1e-5f);
    float4 ga = ((const float4*)g)[fp * 2], gb = ((const float4*)g)[fp * 2 + 1];
    float4 ba = ((const float4*)bb)[fp * 2], bc = ((const float4*)bb)[fp * 2 + 1];
    float gv[8] = {ga.x, ga.y, ga.z, ga.w, gb.x, gb.y, gb.z, gb.w};
    float bv[8] = {ba.x, ba.y, ba.z, ba.w, bc.x, bc.y, bc.z, bc.w};
#pragma unroll
    for (int t = 0; t < 8; t++) y[t] = fmaxf((v[t] - mu) * rstd * gv[t] + bv[t], 0.0f);
}

// ---------------- layer-1 gather (8 nodes/wave) + bias + LN + ReLU -> h1 fp16 ----------------
__global__ __launch_bounds__(256) void gather_ln(const int* __restrict__ offs,
                                                 const int* __restrict__ pdeg,
                                                 const unsigned int* __restrict__ ssrc,
                                                 const float* __restrict__ di,
                                                 const __half* __restrict__ hws,
                                                 const float* __restrict__ cb,
                                                 const float* __restrict__ g,
                                                 const float* __restrict__ bb,
                                                 __half* __restrict__ out) {
    int wv = threadIdx.x >> 6;
    int lane = threadIdx.x & 63;
    int fp = lane & 7, gg = lane >> 3;
    int node = blockIdx.x * 32 + wv * 8 + gg;   // NN % 32 == 0
    float acc[8];
    gather_node8(offs, pdeg, ssrc, hws, node, fp, acc);
    float4 ca = ((const float4*)cb)[fp * 2], cc = ((const float4*)cb)[fp * 2 + 1];
    float cv[8] = {ca.x, ca.y, ca.z, ca.w, cc.x, cc.y, cc.z, cc.w};
    float dn = di[node];
    float v[8], y[8];
#pragma unroll
    for (int t = 0; t < 8; t++) v[t] = acc[t] * dn + cv[t];
    ln8(v, fp, g, bb, y);
    union U { float4 f4; __half2 h2[4]; } u;
#pragma unroll
    for (int t = 0; t < 4; t++) u.h2[t] = __floats2half2_rn(y[2 * t], y[2 * t + 1]);
    ((float4*)(out + (size_t)node * HD))[fp] = u.f4;   // wave writes 1KB contiguous
}

// ---------------- layer-2 gather (8 nodes/wave) + LN + ReLU + skip + pooled scatter ----------------
__global__ __launch_bounds__(256) void gather_ln_pool(const int* __restrict__ offs,
                                                      const int* __restrict__ pdeg,
                                                      const unsigned int* __restrict__ ssrc,
                                                      const float* __restrict__ di,
                                                      const __half* __restrict__ hws,
                                                      const float* __restrict__ cb,
                                                      const float* __restrict__ g,
                                                      const float* __restrict__ bb,
                                                      const __half* __restrict__ h1,
                                                      const int* __restrict__ batch,
                                                      float* __restrict__ readout) {
    int wv = threadIdx.x >> 6;
    int lane = threadIdx.x & 63;
    int fp = lane & 7, gg = lane >> 3;
    int node = blockIdx.x * 32 + wv * 8 + gg;
    float acc[8];
    gather_node8(offs, pdeg, ssrc, hws, node, fp, acc);
    float4 ca = ((const float4*)cb)[fp * 2], cc = ((const float4*)cb)[fp * 2 + 1];
    float cv[8] = {ca.x, ca.y, ca.z, ca.w, cc.x, cc.y, cc.z, cc.w};
    float dn = di[node];
    float v[8], y[8];
#pragma unroll
    for (int t = 0; t < 8; t++) v[t] = acc[t] * dn + cv[t];
    ln8(v, fp, g, bb, y);
    // skip connection: s = relu(ln(conv2)) + h1
    union U { float4 f4; __half2 h2[4]; } u;
    u.f4 = ((const float4*)(h1 + (size_t)node * HD))[fp];
    float s[8];
#pragma unroll
    for (int t = 0; t < 4; t++) {
        float2 p = __half22float2(u.h2[t]);
        s[2 * t]     = y[2 * t] + p.x;
        s[2 * t + 1] = y[2 * t + 1] + p.y;
    }
    // pooled scatter: batch is sorted; a wave's 8 consecutive nodes are
    // usually (~85%) in one group -> cross-group reduce + 64 atomics/wave.
    int b = batch[node];
    int b0 = __shfl(b, 0, 64);
    if (__all(b == b0)) {
#pragma unroll
        for (int t = 0; t < 8; t++) {
            s[t] += __shfl_xor(s[t], 8, 64);
            s[t] += __shfl_xor(s[t], 16, 64);
            s[t] += __shfl_xor(s[t], 32, 64);
        }
        if (gg == 0) {
            float* rp = &readout[(size_t)b0 * HD + fp * 8];
#pragma unroll
            for (int t = 0; t < 8; t++) atomicAdd(&rp[t], s[t]);
        }
    } else {
        float* rp = &readout[(size_t)b * HD + fp * 8];
#pragma unroll
        for (int t = 0; t < 8; t++) atomicAdd(&rp[t], s[t]);
    }
}

// ---------------- final: out = readout @ post_w + post_b  [G,64]@[64,40] ----------------
__global__ __launch_bounds__(256) void out_gemm(const float* __restrict__ r,
                                                const float* __restrict__ w,
                                                const float* __restrict__ b,
                                                float* __restrict__ out) {
    __shared__ float lw[HD * CO];
    for (int i = threadIdx.x; i < HD * CO; i += 256) lw[i] = w[i];
    __syncthreads();
    int grp = blockIdx.x * 4 + (threadIdx.x >> 6);
    int c = threadIdx.x & 63;
    if (grp >= NG || c >= CO) return;
    const float* rr = r + (size_t)grp * HD;
    float acc = b[c];
#pragma unroll 8
    for (int k = 0; k < HD; k++) acc = fmaf(rr[k], lw[k * CO + c], acc);
    out[(size_t)grp * CO + c] = acc;
}

extern "C" void kernel_launch(void* const* d_in, const int* in_sizes, int n_in,
                              void* d_out, int out_size, void* d_ws, size_t ws_size,
                              hipStream_t stream) {
    const float* x      = (const float*)d_in[0];
    const int*   ei     = (const int*)d_in[1];
    const int*   batch  = (const int*)d_in[2];
    const float* pre_w  = (const float*)d_in[3];
    const float* pre_b  = (const float*)d_in[4];
    const float* c1_w   = (const float*)d_in[5];
    const float* c1_b   = (const float*)d_in[6];
    const float* n1_g   = (const float*)d_in[7];
    const float* n1_b   = (const float*)d_in[8];
    const float* c2_w   = (const float*)d_in[9];
    const float* c2_b   = (const float*)d_in[10];
    const float* n2_g   = (const float*)d_in[11];
    const float* n2_b   = (const float*)d_in[12];
    const float* post_w = (const float*)d_in[13];
    const float* post_b = (const float*)d_in[14];

    const int* src = ei;
    const int* dst = ei + NE;

    char* p = (char*)d_ws;
    int*          scur    = (int*)p;          p += (size_t)NSB * 16 * 4;
    int*          offs    = (int*)p;          p += (size_t)NN * 4;
    int*          degn    = (int*)p;          p += (size_t)NN * 4;
    float*        di      = (float*)p;        p += (size_t)NN * 4;
    float*        weff    = (float*)p;        p += (size_t)FIN * HD * 4;
    float*        beff    = (float*)p;        p += 256;
    unsigned int* stmp    = (unsigned int*)p; p += (size_t)NSB * SCAP * 4;
    unsigned int* ssrc    = (unsigned int*)p; p += (size_t)NSB * GCAP * 4;
    float*        readout = (float*)p;        p += (size_t)NG * HD * 4;
    __half*       hws     = (__half*)p;       p += (size_t)(NN + 8) * HD * 2;  // +dummy row
    __half*       h1      = (__half*)p;       p += (size_t)NN * HD * 2;

    // setup: cursors, readout zero, dummy hws row zero
    setup_kernel<<<(NG * HD + 255) / 256, 256, 0, stream>>>(scur, readout,
                                                            (unsigned int*)(hws + (size_t)NN * HD));

    // two-level CSR build: super-bucket scatter -> per-group counting sort
    scatter_super<<<NSCAT, 1024, 0, stream>>>(src, dst, scur, stmp);
    group_sort<<<NSB, 1024, 0, stream>>>(scur, stmp, ssrc, offs, degn, di);

    // Folded pre-MLP weights (one-shot; fusing into gemm1 costs 768x redundant work — R12)
    weff_kernel<<<33, 256, 0, stream>>>(pre_w, pre_b, c1_w, weff, beff);

    // layer 1
    gemm1_tiled<<<768, 256, 0, stream>>>(x, weff, beff, di, hws);
    gather_ln<<<NN / 32, 256, 0, stream>>>(offs, degn, ssrc, di, hws, c1_b, n1_g, n1_b, h1);

    // layer 2
    conv_gemm_tiled<<<1280, 256, 0, stream>>>(h1, c2_w, di, hws);
    gather_ln_pool<<<NN / 32, 256, 0, stream>>>(offs, degn, ssrc, di, hws, c2_b, n2_g, n2_b, h1, batch, readout);

    out_gemm<<<(NG + 3) / 4, 256, 0, stream>>>(readout, post_w, post_b, (float*)d_out);
}

// Round 2
// 275.712 us; speedup vs baseline: 1.1305x; 1.1305x over previous
//
#include <hip/hip_runtime.h>
#include <hip/hip_fp16.h>

#define NN 100000
#define NE 1600000
#define FIN 128
#define HD 64
#define CO 40
#define NG 2048
#define NSB 196           // super-buckets of 512 nodes: ceil(100000/512)
#define SCAP 9216         // super-bucket capacity (mean 8163, +11 sigma)
#define GCAP 13312        // padded ssrc capacity per group (SCAP + 512*7 pad)
#define CHUNK 4096        // edges per scatter block
#define NSCAT ((NE + CHUNK - 1) / CHUNK)   // 391

// ---------------- setup: cursors + zero readout + zero dummy hws row ----------------
__global__ __launch_bounds__(256) void setup_kernel(int* __restrict__ scur,
                                                    float* __restrict__ readout,
                                                    unsigned int* __restrict__ dummy) {
    int gid = blockIdx.x * 256 + threadIdx.x;
    if (gid < NG * HD) readout[gid] = 0.0f;
    if (gid < NSB) scur[gid * 16] = gid * SCAP;
    if (gid < HD / 2) dummy[gid] = 0u;   // 64 halves = 32 uints
}

// =====================================================================
// P1: binned scatter into 196 super-buckets (512 nodes each).
// 1024 threads/block, (dst,src) register-cached across phases (R13).
// =====================================================================
__global__ __launch_bounds__(1024) void scatter_super(const int* __restrict__ src,
                                                      const int* __restrict__ dst,
                                                      int* __restrict__ scur,
                                                      unsigned int* __restrict__ stmp) {
    __shared__ int hist[NSB];
    __shared__ int gbase[NSB];
    int tid = threadIdx.x;
    int e0 = blockIdx.x * CHUNK;
    int d[4], s[4];
    if (tid < NSB) hist[tid] = 0;
    __syncthreads();
#pragma unroll
    for (int r = 0; r < 4; r++) {
        int e = e0 + tid + r * 1024;
        d[r] = -1; s[r] = 0;
        if (e < NE) {
            d[r] = dst[e];
            s[r] = src[e];
            atomicAdd(&hist[d[r] >> 9], 1);
        }
    }
    __syncthreads();
    if (tid < NSB) {
        int c = hist[tid];
        gbase[tid] = (c > 0) ? atomicAdd(&scur[tid * 16], c) : 0;
        hist[tid] = 0;
    }
    __syncthreads();
#pragma unroll
    for (int r = 0; r < 4; r++) {
        if (d[r] >= 0) {
            int b = d[r] >> 9;
            int p = atomicAdd(&hist[b], 1);
            stmp[gbase[b] + p] = ((unsigned int)(d[r] & 511) << 17) | (unsigned int)s[r];
        }
    }
}

// =====================================================================
// P2: per-super-bucket counting sort (512 node bins) -> padded ssrc,
// offs/degn/di. 1024 threads/block; stmp read ONCE via register cache.
// =====================================================================
__global__ __launch_bounds__(1024) void group_sort(const int* __restrict__ scur,
                                                   const unsigned int* __restrict__ stmp,
                                                   unsigned int* __restrict__ ssrc,
                                                   int* __restrict__ offs,
                                                   int* __restrict__ degn,
                                                   float* __restrict__ di) {
    __shared__ int lh[512];
    __shared__ int sc[512];
    __shared__ int lcur[512];
    int g = blockIdx.x;
    int tid = threadIdx.x;
    int base = g * SCAP;
    int cnt = scur[g * 16] - base;
    if (tid < 512) lh[tid] = 0;
    __syncthreads();
    unsigned int uv[9];          // SCAP/1024 == 9 exactly
#pragma unroll
    for (int r = 0; r < 9; r++) {
        int i = tid + r * 1024;
        uv[r] = 0xFFFFFFFFu;     // valid entries are < 2^26, sentinel safe
        if (i < cnt) {
            uv[r] = stmp[base + i];
            atomicAdd(&lh[uv[r] >> 17], 1);
        }
    }
    __syncthreads();
    int h = 0, pd = 0;
    if (tid < 512) {
        h = lh[tid];
        pd = (h + 7) & ~7;
        sc[tid] = pd;
    }
    __syncthreads();
    for (int off = 1; off < 512; off <<= 1) {
        int v = 0;
        if (tid >= off && tid < 512) v = sc[tid - off];
        __syncthreads();
        if (tid < 512) sc[tid] += v;
        __syncthreads();
    }
    if (tid < 512) {
        int excl = sc[tid] - pd;    // exclusive scan of padded counts
        lcur[tid] = excl;
        int node = g * 512 + tid;
        if (node < NN) {
            offs[node] = g * GCAP + excl;
            degn[node] = pd;
            di[node] = rsqrtf((float)h + 1.0f);
        }
        size_t gb = (size_t)g * GCAP;
        for (int q = h; q < pd; q++) ssrc[gb + excl + q] = (unsigned int)NN;  // pads -> zero row
    }
    __syncthreads();
#pragma unroll
    for (int r = 0; r < 9; r++) {
        unsigned int u = uv[r];
        if (u != 0xFFFFFFFFu) {
            int dl = (int)(u >> 17);
            int pos = atomicAdd(&lcur[dl], 1);
            ssrc[(size_t)g * GCAP + pos] = u & 0x1FFFFu;
        }
    }
}

// ---------------- W_eff = pre_w @ c1_w ; b_eff = pre_b @ c1_w (one-shot) ----------------
__global__ __launch_bounds__(256) void weff_kernel(const float* __restrict__ pre_w,
                                                   const float* __restrict__ pre_b,
                                                   const float* __restrict__ c1_w,
                                                   float* __restrict__ weff,
                                                   float* __restrict__ beff) {
    if (blockIdx.x < 32) {
        int o = blockIdx.x * 256 + threadIdx.x;
        int r = o >> 6, c = o & 63;
        float acc = 0.0f;
#pragma unroll 8
        for (int k = 0; k < HD; k++) acc = fmaf(pre_w[r * HD + k], c1_w[k * HD + c], acc);
        weff[o] = acc;
    } else {
        int c = threadIdx.x;
        if (c < HD) {
            float acc = 0.0f;
#pragma unroll 8
            for (int k = 0; k < HD; k++) acc = fmaf(pre_b[k], c1_w[k * HD + c], acc);
            beff[c] = acc;
        }
    }
}

// =====================================================================
// Tiled GEMM 1: hws = half((x @ W_eff + b_eff) * di)   [N,128]@[128,64]
// =====================================================================
__global__ __launch_bounds__(256) void gemm1_tiled(const float* __restrict__ x,
                                                   const float* __restrict__ w,
                                                   const float* __restrict__ b,
                                                   const float* __restrict__ di,
                                                   __half* __restrict__ hws) {
    __shared__ float wS[FIN * HD];   // 32 KB
    __shared__ float xS[64 * 64];    // 16 KB (one K-half)
    int tid = threadIdx.x;
    for (int i = tid; i < FIN * HD; i += 256) wS[i] = w[i];
    int tn = tid & 15, tf = tid >> 4;
    int f0 = tf * 4;
    float4 bv = ((const float4*)b)[tf];
    int ntiles = (NN + 63) >> 6;
    for (int t = blockIdx.x; t < ntiles; t += gridDim.x) {
        int nb = t << 6;
        float acc[4][4];
#pragma unroll
        for (int i = 0; i < 4; i++)
#pragma unroll
            for (int j = 0; j < 4; j++) acc[i][j] = 0.0f;
        for (int kh = 0; kh < 2; kh++) {
            __syncthreads();
            {
                int n_l = tid >> 4;
                int k4l = tid & 15;
                for (int r = 0; r < 4; r++) {
                    int n = n_l + r * 16;
                    int row = nb + n;
                    float4 v = make_float4(0.f, 0.f, 0.f, 0.f);
                    if (row < NN) v = ((const float4*)(x + (size_t)row * FIN))[kh * 16 + k4l];
                    int g = n >> 2, nl2 = n & 3;
                    const float* vp = (const float*)&v;
#pragma unroll
                    for (int j = 0; j < 4; j++) {
                        int k = k4l * 4 + j;
                        int gp = g ^ (k & 15);
                        xS[k * 64 + gp * 4 + nl2] = vp[j];
                    }
                }
            }
            __syncthreads();
#pragma unroll 4
            for (int kl = 0; kl < 64; kl++) {
                int gp = tn ^ (kl & 15);
                float4 xv = *(const float4*)&xS[kl * 64 + gp * 4];
                float4 wv = *(const float4*)&wS[(kh * 64 + kl) * 64 + f0];
                acc[0][0] = fmaf(xv.x, wv.x, acc[0][0]); acc[0][1] = fmaf(xv.x, wv.y, acc[0][1]);
                acc[0][2] = fmaf(xv.x, wv.z, acc[0][2]); acc[0][3] = fmaf(xv.x, wv.w, acc[0][3]);
                acc[1][0] = fmaf(xv.y, wv.x, acc[1][0]); acc[1][1] = fmaf(xv.y, wv.y, acc[1][1]);
                acc[1][2] = fmaf(xv.y, wv.z, acc[1][2]); acc[1][3] = fmaf(xv.y, wv.w, acc[1][3]);
                acc[2][0] = fmaf(xv.z, wv.x, acc[2][0]); acc[2][1] = fmaf(xv.z, wv.y, acc[2][1]);
                acc[2][2] = fmaf(xv.z, wv.z, acc[2][2]); acc[2][3] = fmaf(xv.z, wv.w, acc[2][3]);
                acc[3][0] = fmaf(xv.w, wv.x, acc[3][0]); acc[3][1] = fmaf(xv.w, wv.y, acc[3][1]);
                acc[3][2] = fmaf(xv.w, wv.z, acc[3][2]); acc[3][3] = fmaf(xv.w, wv.w, acc[3][3]);
            }
        }
        int n0 = nb + tn * 4;
#pragma unroll
        for (int i = 0; i < 4; i++) {
            int n = n0 + i;
            if (n < NN) {
                float dn = di[n];
                __half2 p0 = __floats2half2_rn((acc[i][0] + bv.x) * dn, (acc[i][1] + bv.y) * dn);
                __half2 p1 = __floats2half2_rn((acc[i][2] + bv.z) * dn, (acc[i][3] + bv.w) * dn);
                __half2* o = (__half2*)(hws + (size_t)n * HD + f0);
                o[0] = p0; o[1] = p1;
            }
        }
    }
}

// =====================================================================
// Tiled GEMM 2: hws = half((h1 @ c2_w) * di)   [N,64]@[64,64], h1 fp16
// =====================================================================
__global__ __launch_bounds__(256) void conv_gemm_tiled(const __half* __restrict__ hin,
                                                       const float* __restrict__ w,
                                                       const float* __restrict__ di,
                                                       __half* __restrict__ hws) {
    __shared__ float wS[HD * HD];
    __shared__ float xS[64 * HD];
    int tid = threadIdx.x;
    for (int i = tid; i < HD * HD; i += 256) wS[i] = w[i];
    int tn = tid & 15, tf = tid >> 4;
    int f0 = tf * 4;
    int ntiles = (NN + 63) >> 6;
    for (int t = blockIdx.x; t < ntiles; t += gridDim.x) {
        int nb = t << 6;
        __syncthreads();
        {
            int n_l = tid >> 3;
            int k8 = tid & 7;
            union U { float4 f4; __half2 h2[4]; } u;
            for (int r = 0; r < 2; r++) {
                int n = n_l + r * 32;
                int row = nb + n;
                u.f4 = make_float4(0.f, 0.f, 0.f, 0.f);
                if (row < NN) u.f4 = ((const float4*)(hin + (size_t)row * HD))[k8];
                int g = n >> 2, nl2 = n & 3;
#pragma unroll
                for (int j = 0; j < 4; j++) {
                    float2 p = __half22float2(u.h2[j]);
                    int k = k8 * 8 + 2 * j;
                    int gp = g ^ (k & 15);
                    xS[k * 64 + gp * 4 + nl2] = p.x;
                    int k2 = k + 1;
                    int gp2 = g ^ (k2 & 15);
                    xS[k2 * 64 + gp2 * 4 + nl2] = p.y;
                }
            }
        }
        __syncthreads();
        float acc[4][4];
#pragma unroll
        for (int i = 0; i < 4; i++)
#pragma unroll
            for (int j = 0; j < 4; j++) acc[i][j] = 0.0f;
#pragma unroll 4
        for (int k = 0; k < HD; k++) {
            int gp = tn ^ (k & 15);
            float4 xv = *(const float4*)&xS[k * 64 + gp * 4];
            float4 wv = *(const float4*)&wS[k * 64 + f0];
            acc[0][0] = fmaf(xv.x, wv.x, acc[0][0]); acc[0][1] = fmaf(xv.x, wv.y, acc[0][1]);
            acc[0][2] = fmaf(xv.x, wv.z, acc[0][2]); acc[0][3] = fmaf(xv.x, wv.w, acc[0][3]);
            acc[1][0] = fmaf(xv.y, wv.x, acc[1][0]); acc[1][1] = fmaf(xv.y, wv.y, acc[1][1]);
            acc[1][2] = fmaf(xv.y, wv.z, acc[1][2]); acc[1][3] = fmaf(xv.y, wv.w, acc[1][3]);
            acc[2][0] = fmaf(xv.z, wv.x, acc[2][0]); acc[2][1] = fmaf(xv.z, wv.y, acc[2][1]);
            acc[2][2] = fmaf(xv.z, wv.z, acc[2][2]); acc[2][3] = fmaf(xv.z, wv.w, acc[2][3]);
            acc[3][0] = fmaf(xv.w, wv.x, acc[3][0]); acc[3][1] = fmaf(xv.w, wv.y, acc[3][1]);
            acc[3][2] = fmaf(xv.w, wv.z, acc[3][2]); acc[3][3] = fmaf(xv.w, wv.w, acc[3][3]);
        }
        int n0 = nb + tn * 4;
#pragma unroll
        for (int i = 0; i < 4; i++) {
            int n = n0 + i;
            if (n < NN) {
                float dn = di[n];
                __half2 p0 = __floats2half2_rn(acc[i][0] * dn, acc[i][1] * dn);
                __half2 p1 = __floats2half2_rn(acc[i][2] * dn, acc[i][3] * dn);
                __half2* o = (__half2*)(hws + (size_t)n * HD + f0);
                o[0] = p0; o[1] = p1;
            }
        }
    }
}

// =====================================================================
// Gather core (R14): one node per 8-lane group, 8 edges/iteration,
// TWO-DEEP index prefetch (idx for it+2 issued before rows of it) so
// row-load addresses never wait on an index round trip. Launch bounds
// (256,4) allow ~128 VGPRs so all 8 row loads stay in flight (R13's 36
// VGPRs forced the compiler to serialize them).
// =====================================================================
__device__ __forceinline__ void gather_node8(const int* __restrict__ offs,
                                             const int* __restrict__ pdeg,
                                             const unsigned int* __restrict__ ssrc,
                                             const __half* __restrict__ hws,
                                             int node, int fp, float acc[8]) {
    int i0 = offs[node];
    int deg = pdeg[node];                    // multiple of 8 (may be 0)
    const uint4* ip = (const uint4*)(ssrc + i0);     // 16B-aligned (offs multiple of 8)
    union U { float4 f4; __half2 h2[4]; } u[8];
    __half2 hacc[4][4];
#pragma unroll
    for (int s = 0; s < 4; s++)
#pragma unroll
        for (int t = 0; t < 4; t++) hacc[s][t] = __floats2half2_rn(0.f, 0.f);
    // self-loop row
    u[0].f4 = ((const float4*)(hws + (size_t)node * HD))[fp];
#pragma unroll
    for (int t = 0; t < 4; t++) hacc[0][t] = u[0].h2[t];
    int nit = deg >> 3;
    if (nit > 0) {
        uint4 a0 = ip[0], b0 = ip[1];
        uint4 a1 = make_uint4(0u, 0u, 0u, 0u), b1 = a1;
        if (nit > 1) { a1 = ip[2]; b1 = ip[3]; }
        for (int it = 0; it < nit; ++it) {
            bool more = (it + 2 < nit);
            uint4 a2 = a1, b2 = b1;
            if (more) { a2 = ip[2 * it + 4]; b2 = ip[2 * it + 5]; }   // idx for it+2
            u[0].f4 = ((const float4*)(hws + (size_t)a0.x * HD))[fp];
            u[1].f4 = ((const float4*)(hws + (size_t)a0.y * HD))[fp];
            u[2].f4 = ((const float4*)(hws + (size_t)a0.z * HD))[fp];
            u[3].f4 = ((const float4*)(hws + (size_t)a0.w * HD))[fp];
            u[4].f4 = ((const float4*)(hws + (size_t)b0.x * HD))[fp];
            u[5].f4 = ((const float4*)(hws + (size_t)b0.y * HD))[fp];
            u[6].f4 = ((const float4*)(hws + (size_t)b0.z * HD))[fp];
            u[7].f4 = ((const float4*)(hws + (size_t)b0.w * HD))[fp];
#pragma unroll
            for (int q = 0; q < 8; q++)
#pragma unroll
                for (int t = 0; t < 4; t++)
                    hacc[q & 3][t] = __hadd2(hacc[q & 3][t], u[q].h2[t]);
            a0 = a1; b0 = b1;
            a1 = a2; b1 = b2;
        }
    }
    // combine the 4 half2 sets in fp32
#pragma unroll
    for (int t = 0; t < 4; t++) {
        float2 a = __half22float2(hacc[0][t]);
        float2 b = __half22float2(hacc[1][t]);
        float2 c = __half22float2(hacc[2][t]);
        float2 d = __half22float2(hacc[3][t]);
        acc[2 * t]     = (a.x + b.x) + (c.x + d.x);
        acc[2 * t + 1] = (a.y + b.y) + (c.y + d.y);
    }
}

// LN over the 8-features-per-lane layout; xor 1,2,4 stays inside the
// 8-lane group (lane bits 0..2 == fp). Returns relu'd y[8].
__device__ __forceinline__ void ln8(float v[8], int fp,
                                    const float* __restrict__ g,
                                    const float* __restrict__ bb,
                                    float y[8]) {
    float su = 0.0f;
#pragma unroll
    for (int t = 0; t < 8; t++) su += v[t];
    su += __shfl_xor(su, 1, 64); su += __shfl_xor(su, 2, 64); su += __shfl_xor(su, 4, 64);
    float mu = su * (1.0f / HD);
    float q = 0.0f;
#pragma unroll
    for (int t = 0; t < 8; t++) { float d = v[t] - mu; q += d * d; }
    q += __shfl_xor(q, 1, 64); q += __shfl_xor(q, 2, 64); q += __shfl_xor(q, 4, 64);
    float rstd = rsqrtf(q * (1.0f / HD) + 1e-5f);
    float4 ga = ((const float4*)g)[fp * 2], gb = ((const float4*)g)[fp * 2 + 1];
    float4 ba = ((const float4*)bb)[fp * 2], bc = ((const float4*)bb)[fp * 2 + 1];
    float gv[8] = {ga.x, ga.y, ga.z, ga.w, gb.x, gb.y, gb.z, gb.w};
    float bv[8] = {ba.x, ba.y, ba.z, ba.w, bc.x, bc.y, bc.z, bc.w};
#pragma unroll
    for (int t = 0; t < 8; t++) y[t] = fmaxf((v[t] - mu) * rstd * gv[t] + bv[t], 0.0f);
}

// ---------------- layer-1 gather (8 nodes/wave) + bias + LN + ReLU -> h1 fp16 ----------------
__global__ __launch_bounds__(256, 4) void gather_ln(const int* __restrict__ offs,
                                                    const int* __restrict__ pdeg,
                                                    const unsigned int* __restrict__ ssrc,
                                                    const float* __restrict__ di,
                                                    const __half* __restrict__ hws,
                                                    const float* __restrict__ cb,
                                                    const float* __restrict__ g,
                                                    const float* __restrict__ bb,
                                                    __half* __restrict__ out) {
    int wv = threadIdx.x >> 6;
    int lane = threadIdx.x & 63;
    int fp = lane & 7, gg = lane >> 3;
    int node = blockIdx.x * 32 + wv * 8 + gg;   // NN % 32 == 0
    float acc[8];
    gather_node8(offs, pdeg, ssrc, hws, node, fp, acc);
    float4 ca = ((const float4*)cb)[fp * 2], cc = ((const float4*)cb)[fp * 2 + 1];
    float cv[8] = {ca.x, ca.y, ca.z, ca.w, cc.x, cc.y, cc.z, cc.w};
    float dn = di[node];
    float v[8], y[8];
#pragma unroll
    for (int t = 0; t < 8; t++) v[t] = acc[t] * dn + cv[t];
    ln8(v, fp, g, bb, y);
    union U { float4 f4; __half2 h2[4]; } u;
#pragma unroll
    for (int t = 0; t < 4; t++) u.h2[t] = __floats2half2_rn(y[2 * t], y[2 * t + 1]);
    ((float4*)(out + (size_t)node * HD))[fp] = u.f4;   // wave writes 1KB contiguous
}

// ---------------- layer-2 gather (8 nodes/wave) + LN + ReLU + skip + pooled scatter ----------------
// R14: epilogue transposes via LDS (stride 65 -> conflict-free) back to
// feature-parallel, 64-lane CONTIGUOUS atomics (R13's per-lane serial
// atomics caused 50 MB of RMW writethrough; predict ~5 MB).
__global__ __launch_bounds__(256, 4) void gather_ln_pool(const int* __restrict__ offs,
                                                         const int* __restrict__ pdeg,
                                                         const unsigned int* __restrict__ ssrc,
                                                         const float* __restrict__ di,
                                                         const __half* __restrict__ hws,
                                                         const float* __restrict__ cb,
                                                         const float* __restrict__ g,
                                                         const float* __restrict__ bb,
                                                         const __half* __restrict__ h1,
                                                         const int* __restrict__ batch,
                                                         float* __restrict__ readout) {
    __shared__ float ls[32][65];   // 32 nodes/block, stride 65: write banks (g+8fp+t)%32 -> 2-way (free)
    __shared__ int lb[32];
    int wv = threadIdx.x >> 6;
    int lane = threadIdx.x & 63;
    int fp = lane & 7, gg = lane >> 3;
    int node = blockIdx.x * 32 + wv * 8 + gg;
    float acc[8];
    gather_node8(offs, pdeg, ssrc, hws, node, fp, acc);
    float4 ca = ((const float4*)cb)[fp * 2], cc = ((const float4*)cb)[fp * 2 + 1];
    float cv[8] = {ca.x, ca.y, ca.z, ca.w, cc.x, cc.y, cc.z, cc.w};
    float dn = di[node];
    float v[8], y[8];
#pragma unroll
    for (int t = 0; t < 8; t++) v[t] = acc[t] * dn + cv[t];
    ln8(v, fp, g, bb, y);
    // skip connection: s = relu(ln(conv2)) + h1
    union U { float4 f4; __half2 h2[4]; } u;
    u.f4 = ((const float4*)(h1 + (size_t)node * HD))[fp];
    int row = wv * 8 + gg;
#pragma unroll
    for (int t = 0; t < 4; t++) {
        float2 p = __half22float2(u.h2[t]);
        ls[row][fp * 8 + 2 * t]     = y[2 * t] + p.x;
        ls[row][fp * 8 + 2 * t + 1] = y[2 * t + 1] + p.y;
    }
    if (fp == 0) lb[row] = batch[node];
    // rows of this wave are wave-private: per-wave DS ordering suffices, no __syncthreads
    int r0 = wv * 8;
    int bu = lb[r0];
    bool uni = true;
#pragma unroll
    for (int r = 1; r < 8; r++) uni = uni && (lb[r0 + r] == bu);
    int f = lane;
    if (uni) {
        float s2 = 0.0f;
#pragma unroll
        for (int r = 0; r < 8; r++) s2 += ls[r0 + r][f];
        atomicAdd(&readout[(size_t)bu * HD + f], s2);   // 64-lane contiguous
    } else {
        // batch sorted within the wave's 8 rows: merge equal runs
        float s2 = ls[r0][f];
        int bprev = lb[r0];
#pragma unroll
        for (int r = 1; r < 8; r++) {
            int bn = lb[r0 + r];
            if (bn == bprev) {
                s2 += ls[r0 + r][f];
            } else {
                atomicAdd(&readout[(size_t)bprev * HD + f], s2);
                s2 = ls[r0 + r][f];
                bprev = bn;
            }
        }
        atomicAdd(&readout[(size_t)bprev * HD + f], s2);
    }
}

// ---------------- final: out = readout @ post_w + post_b  [G,64]@[64,40] ----------------
__global__ __launch_bounds__(256) void out_gemm(const float* __restrict__ r,
                                                const float* __restrict__ w,
                                                const float* __restrict__ b,
                                                float* __restrict__ out) {
    __shared__ float lw[HD * CO];
    for (int i = threadIdx.x; i < HD * CO; i += 256) lw[i] = w[i];
    __syncthreads();
    int grp = blockIdx.x * 4 + (threadIdx.x >> 6);
    int c = threadIdx.x & 63;
    if (grp >= NG || c >= CO) return;
    const float* rr = r + (size_t)grp * HD;
    float acc = b[c];
#pragma unroll 8
    for (int k = 0; k < HD; k++) acc = fmaf(rr[k], lw[k * CO + c], acc);
    out[(size_t)grp * CO + c] = acc;
}

extern "C" void kernel_launch(void* const* d_in, const int* in_sizes, int n_in,
                              void* d_out, int out_size, void* d_ws, size_t ws_size,
                              hipStream_t stream) {
    const float* x      = (const float*)d_in[0];
    const int*   ei     = (const int*)d_in[1];
    const int*   batch  = (const int*)d_in[2];
    const float* pre_w  = (const float*)d_in[3];
    const float* pre_b  = (const float*)d_in[4];
    const float* c1_w   = (const float*)d_in[5];
    const float* c1_b   = (const float*)d_in[6];
    const float* n1_g   = (const float*)d_in[7];
    const float* n1_b   = (const float*)d_in[8];
    const float* c2_w   = (const float*)d_in[9];
    const float* c2_b   = (const float*)d_in[10];
    const float* n2_g   = (const float*)d_in[11];
    const float* n2_b   = (const float*)d_in[12];
    const float* post_w = (const float*)d_in[13];
    const float* post_b = (const float*)d_in[14];

    const int* src = ei;
    const int* dst = ei + NE;

    char* p = (char*)d_ws;
    int*          scur    = (int*)p;          p += (size_t)NSB * 16 * 4;
    int*          offs    = (int*)p;          p += (size_t)NN * 4;
    int*          degn    = (int*)p;          p += (size_t)NN * 4;
    float*        di      = (float*)p;        p += (size_t)NN * 4;
    float*        weff    = (float*)p;        p += (size_t)FIN * HD * 4;
    float*        beff    = (float*)p;        p += 256;
    unsigned int* stmp    = (unsigned int*)p; p += (size_t)NSB * SCAP * 4;
    unsigned int* ssrc    = (unsigned int*)p; p += (size_t)NSB * GCAP * 4;
    float*        readout = (float*)p;        p += (size_t)NG * HD * 4;
    __half*       hws     = (__half*)p;       p += (size_t)(NN + 8) * HD * 2;  // +dummy row
    __half*       h1      = (__half*)p;       p += (size_t)NN * HD * 2;

    // setup: cursors, readout zero, dummy hws row zero
    setup_kernel<<<(NG * HD + 255) / 256, 256, 0, stream>>>(scur, readout,
                                                            (unsigned int*)(hws + (size_t)NN * HD));

    // two-level CSR build: super-bucket scatter -> per-group counting sort
    scatter_super<<<NSCAT, 1024, 0, stream>>>(src, dst, scur, stmp);
    group_sort<<<NSB, 1024, 0, stream>>>(scur, stmp, ssrc, offs, degn, di);

    // Folded pre-MLP weights (one-shot; fusing into gemm1 costs 768x redundant work — R12)
    weff_kernel<<<33, 256, 0, stream>>>(pre_w, pre_b, c1_w, weff, beff);

    // layer 1
    gemm1_tiled<<<768, 256, 0, stream>>>(x, weff, beff, di, hws);
    gather_ln<<<NN / 32, 256, 0, stream>>>(offs, degn, ssrc, di, hws, c1_b, n1_g, n1_b, h1);

    // layer 2
    conv_gemm_tiled<<<1280, 256, 0, stream>>>(h1, c2_w, di, hws);
    gather_ln_pool<<<NN / 32, 256, 0, stream>>>(offs, degn, ssrc, di, hws, c2_b, n2_g, n2_b, h1, batch, readout);

    out_gemm<<<(NG + 3) / 4, 256, 0, stream>>>(readout, post_w, post_b, (float*)d_out);
}

// Round 3
// 243.496 us; speedup vs baseline: 1.2800x; 1.1323x over previous
//
#include <hip/hip_runtime.h>
#include <hip/hip_fp16.h>

#define NN 100000
#define NE 1600000
#define FIN 128
#define HD 64
#define CO 40
#define NG 2048
#define NSB 196           // super-buckets of 512 nodes: ceil(100000/512)
#define SCAP 9216         // super-bucket capacity (mean 8163, +11 sigma)
#define GCAP 13312        // padded ssrc capacity per group (SCAP + 512*7 pad)
#define CHUNK 4096        // edges per scatter block
#define NSCAT ((NE + CHUNK - 1) / CHUNK)   // 391

typedef _Float16 half8 __attribute__((ext_vector_type(8)));
typedef float floatx4 __attribute__((ext_vector_type(4)));

// ---------------- setup: cursors + zero readout + zero dummy hws row ----------------
__global__ __launch_bounds__(256) void setup_kernel(int* __restrict__ scur,
                                                    float* __restrict__ readout,
                                                    unsigned int* __restrict__ dummy) {
    int gid = blockIdx.x * 256 + threadIdx.x;
    if (gid < NG * HD) readout[gid] = 0.0f;
    if (gid < NSB) scur[gid * 16] = gid * SCAP;
    if (gid < HD / 2) dummy[gid] = 0u;   // 64 halves = 32 uints
}

// =====================================================================
// P1: binned scatter into 196 super-buckets (512 nodes each).
// 1024 threads/block, (dst,src) register-cached across phases (R13).
// =====================================================================
__global__ __launch_bounds__(1024) void scatter_super(const int* __restrict__ src,
                                                      const int* __restrict__ dst,
                                                      int* __restrict__ scur,
                                                      unsigned int* __restrict__ stmp) {
    __shared__ int hist[NSB];
    __shared__ int gbase[NSB];
    int tid = threadIdx.x;
    int e0 = blockIdx.x * CHUNK;
    int d[4], s[4];
    if (tid < NSB) hist[tid] = 0;
    __syncthreads();
#pragma unroll
    for (int r = 0; r < 4; r++) {
        int e = e0 + tid + r * 1024;
        d[r] = -1; s[r] = 0;
        if (e < NE) {
            d[r] = dst[e];
            s[r] = src[e];
            atomicAdd(&hist[d[r] >> 9], 1);
        }
    }
    __syncthreads();
    if (tid < NSB) {
        int c = hist[tid];
        gbase[tid] = (c > 0) ? atomicAdd(&scur[tid * 16], c) : 0;
        hist[tid] = 0;
    }
    __syncthreads();
#pragma unroll
    for (int r = 0; r < 4; r++) {
        if (d[r] >= 0) {
            int b = d[r] >> 9;
            int p = atomicAdd(&hist[b], 1);
            stmp[gbase[b] + p] = ((unsigned int)(d[r] & 511) << 17) | (unsigned int)s[r];
        }
    }
}

// =====================================================================
// P2: per-super-bucket counting sort (512 node bins) -> padded ssrc,
// offs/degn/di. 1024 threads/block; stmp read ONCE via register cache.
// =====================================================================
__global__ __launch_bounds__(1024) void group_sort(const int* __restrict__ scur,
                                                   const unsigned int* __restrict__ stmp,
                                                   unsigned int* __restrict__ ssrc,
                                                   int* __restrict__ offs,
                                                   int* __restrict__ degn,
                                                   float* __restrict__ di) {
    __shared__ int lh[512];
    __shared__ int sc[512];
    __shared__ int lcur[512];
    int g = blockIdx.x;
    int tid = threadIdx.x;
    int base = g * SCAP;
    int cnt = scur[g * 16] - base;
    if (tid < 512) lh[tid] = 0;
    __syncthreads();
    unsigned int uv[9];          // SCAP/1024 == 9 exactly
#pragma unroll
    for (int r = 0; r < 9; r++) {
        int i = tid + r * 1024;
        uv[r] = 0xFFFFFFFFu;     // valid entries are < 2^26, sentinel safe
        if (i < cnt) {
            uv[r] = stmp[base + i];
            atomicAdd(&lh[uv[r] >> 17], 1);
        }
    }
    __syncthreads();
    int h = 0, pd = 0;
    if (tid < 512) {
        h = lh[tid];
        pd = (h + 7) & ~7;
        sc[tid] = pd;
    }
    __syncthreads();
    for (int off = 1; off < 512; off <<= 1) {
        int v = 0;
        if (tid >= off && tid < 512) v = sc[tid - off];
        __syncthreads();
        if (tid < 512) sc[tid] += v;
        __syncthreads();
    }
    if (tid < 512) {
        int excl = sc[tid] - pd;    // exclusive scan of padded counts
        lcur[tid] = excl;
        int node = g * 512 + tid;
        if (node < NN) {
            offs[node] = g * GCAP + excl;
            degn[node] = pd;
            di[node] = rsqrtf((float)h + 1.0f);
        }
        size_t gb = (size_t)g * GCAP;
        for (int q = h; q < pd; q++) ssrc[gb + excl + q] = (unsigned int)NN;  // pads -> zero row
    }
    __syncthreads();
#pragma unroll
    for (int r = 0; r < 9; r++) {
        unsigned int u = uv[r];
        if (u != 0xFFFFFFFFu) {
            int dl = (int)(u >> 17);
            int pos = atomicAdd(&lcur[dl], 1);
            ssrc[(size_t)g * GCAP + pos] = u & 0x1FFFFu;
        }
    }
}

// ---------------- one-shot weight prep ----------------
// blocks 0..31 : wth  = (pre_w @ c1_w)^T  as fp16  [64 n][128 k]
// block  32    : beff = pre_b @ c1_w (fp32)
// blocks 33..48: wt2h = c2_w^T as fp16            [64 n][64 k]
__global__ __launch_bounds__(256) void weff_kernel(const float* __restrict__ pre_w,
                                                   const float* __restrict__ pre_b,
                                                   const float* __restrict__ c1_w,
                                                   const float* __restrict__ c2_w,
                                                   _Float16* __restrict__ wth,
                                                   float* __restrict__ beff,
                                                   _Float16* __restrict__ wt2h) {
    int b = blockIdx.x;
    if (b < 32) {
        int o = b * 256 + threadIdx.x;
        int r = o >> 6, c = o & 63;
        float acc = 0.0f;
#pragma unroll 8
        for (int k = 0; k < HD; k++) acc = fmaf(pre_w[r * HD + k], c1_w[k * HD + c], acc);
        wth[c * FIN + r] = (_Float16)acc;
    } else if (b == 32) {
        int c = threadIdx.x;
        if (c < HD) {
            float acc = 0.0f;
#pragma unroll 8
            for (int k = 0; k < HD; k++) acc = fmaf(pre_b[k], c1_w[k * HD + c], acc);
            beff[c] = acc;
        }
    } else {
        int o = (b - 33) * 256 + threadIdx.x;   // 0..4095
        int r = o >> 6, c = o & 63;
        wt2h[c * HD + r] = (_Float16)c2_w[o];
    }
}

// =====================================================================
// R15: MFMA GEMM 1: hws = half((x @ W_eff + b_eff) * di)  [N,128]@[128,64]
// W^T fp16 held ENTIRELY in per-wave registers (16 frags = 64 VGPR) ->
// A (x rows) streams straight HBM->regs->MFMA, zero LDS in the K-loop.
// Old VALU version was LDS-BW-bound at 42us; memory floor here is ~10us.
// A/B use the same (lane,e)->k convention so any k-permutation error
// cancels; C/D layout is the HW-verified col=lane&15,row=(lane>>4)*4+reg.
// =====================================================================
__global__ __launch_bounds__(256, 4) void gemm1_mfma(const float* __restrict__ x,
                                                     const _Float16* __restrict__ wt,
                                                     const float* __restrict__ beff,
                                                     const float* __restrict__ di,
                                                     __half* __restrict__ hws) {
    __shared__ _Float16 wS[64 * 136];   // [n][k] padded 128->136 (bank-spread)
    int tid = threadIdx.x;
    for (int i = tid; i < 1024; i += 256) {          // 1024 x uint4 = 8192 halves
        int n = i >> 4, k0 = (i & 15) * 8;
        *(uint4*)&wS[n * 136 + k0] = ((const uint4*)wt)[i];
    }
    __syncthreads();
    int wv = tid >> 6, lane = tid & 63;
    int l15 = lane & 15, lg = lane >> 4;
    int rbase = blockIdx.x * 64 + wv * 16;
    if (rbase >= NN) return;                         // NN%16==0: whole-tile skip only
    half8 bf[4][4];                                  // [ks][ns] B-fragments (W), 64 VGPR
#pragma unroll
    for (int ks = 0; ks < 4; ks++)
#pragma unroll
        for (int ns = 0; ns < 4; ns++)
            bf[ks][ns] = *(const half8*)&wS[(ns * 16 + l15) * 136 + ks * 32 + lg * 8];
    floatx4 acc[4];
#pragma unroll
    for (int ns = 0; ns < 4; ns++) acc[ns] = (floatx4){0.f, 0.f, 0.f, 0.f};
    const float* xrow = x + (size_t)(rbase + l15) * FIN;
#pragma unroll
    for (int ks = 0; ks < 4; ks++) {
        float4 lo = *(const float4*)(xrow + ks * 32 + lg * 8);
        float4 hi = *(const float4*)(xrow + ks * 32 + lg * 8 + 4);
        half8 a;
        a[0] = (_Float16)lo.x; a[1] = (_Float16)lo.y; a[2] = (_Float16)lo.z; a[3] = (_Float16)lo.w;
        a[4] = (_Float16)hi.x; a[5] = (_Float16)hi.y; a[6] = (_Float16)hi.z; a[7] = (_Float16)hi.w;
#pragma unroll
        for (int ns = 0; ns < 4; ns++)
            acc[ns] = __builtin_amdgcn_mfma_f32_16x16x32_f16(a, bf[ks][ns], acc[ns], 0, 0, 0);
    }
    int r0 = rbase + lg * 4;
#pragma unroll
    for (int ns = 0; ns < 4; ns++) {
        float be = beff[ns * 16 + l15];
#pragma unroll
        for (int r = 0; r < 4; r++) {
            float dn = di[r0 + r];
            hws[(size_t)(r0 + r) * HD + ns * 16 + l15] = __float2half((acc[ns][r] + be) * dn);
        }
    }
}

// =====================================================================
// R15: MFMA GEMM 2: hws = half((h1 @ c2_w) * di)  [N,64]@[64,64], h1 fp16
// Input already fp16: A-frag is one 16B load per K-step. W^T in regs.
// =====================================================================
__global__ __launch_bounds__(256, 4) void conv_gemm_mfma(const __half* __restrict__ hin,
                                                         const _Float16* __restrict__ wt2,
                                                         const float* __restrict__ di,
                                                         __half* __restrict__ hws) {
    __shared__ _Float16 wS[64 * 72];    // [n][k] padded 64->72
    int tid = threadIdx.x;
    for (int i = tid; i < 512; i += 256) {           // 512 x uint4 = 4096 halves
        int n = i >> 3, k0 = (i & 7) * 8;
        *(uint4*)&wS[n * 72 + k0] = ((const uint4*)wt2)[i];
    }
    __syncthreads();
    int wv = tid >> 6, lane = tid & 63;
    int l15 = lane & 15, lg = lane >> 4;
    int rbase = blockIdx.x * 64 + wv * 16;
    if (rbase >= NN) return;
    half8 bf[2][4];                                  // [ks][ns], 32 VGPR
#pragma unroll
    for (int ks = 0; ks < 2; ks++)
#pragma unroll
        for (int ns = 0; ns < 4; ns++)
            bf[ks][ns] = *(const half8*)&wS[(ns * 16 + l15) * 72 + ks * 32 + lg * 8];
    floatx4 acc[4];
#pragma unroll
    for (int ns = 0; ns < 4; ns++) acc[ns] = (floatx4){0.f, 0.f, 0.f, 0.f};
    const __half* hrow = hin + (size_t)(rbase + l15) * HD;
#pragma unroll
    for (int ks = 0; ks < 2; ks++) {
        half8 a = *(const half8*)(hrow + ks * 32 + lg * 8);
#pragma unroll
        for (int ns = 0; ns < 4; ns++)
            acc[ns] = __builtin_amdgcn_mfma_f32_16x16x32_f16(a, bf[ks][ns], acc[ns], 0, 0, 0);
    }
    int r0 = rbase + lg * 4;
#pragma unroll
    for (int ns = 0; ns < 4; ns++) {
#pragma unroll
        for (int r = 0; r < 4; r++) {
            float dn = di[r0 + r];
            hws[(size_t)(r0 + r) * HD + ns * 16 + l15] = __float2half(acc[ns][r] * dn);
        }
    }
}

// =====================================================================
// Gather core (R14): one node per 8-lane group, 8 edges/iteration,
// TWO-DEEP index prefetch; launch bounds (256,4) keep 8 loads in flight.
// =====================================================================
__device__ __forceinline__ void gather_node8(const int* __restrict__ offs,
                                             const int* __restrict__ pdeg,
                                             const unsigned int* __restrict__ ssrc,
                                             const __half* __restrict__ hws,
                                             int node, int fp, float acc[8]) {
    int i0 = offs[node];
    int deg = pdeg[node];                    // multiple of 8 (may be 0)
    const uint4* ip = (const uint4*)(ssrc + i0);     // 16B-aligned (offs multiple of 8)
    union U { float4 f4; __half2 h2[4]; } u[8];
    __half2 hacc[4][4];
#pragma unroll
    for (int s = 0; s < 4; s++)
#pragma unroll
        for (int t = 0; t < 4; t++) hacc[s][t] = __floats2half2_rn(0.f, 0.f);
    // self-loop row
    u[0].f4 = ((const float4*)(hws + (size_t)node * HD))[fp];
#pragma unroll
    for (int t = 0; t < 4; t++) hacc[0][t] = u[0].h2[t];
    int nit = deg >> 3;
    if (nit > 0) {
        uint4 a0 = ip[0], b0 = ip[1];
        uint4 a1 = make_uint4(0u, 0u, 0u, 0u), b1 = a1;
        if (nit > 1) { a1 = ip[2]; b1 = ip[3]; }
        for (int it = 0; it < nit; ++it) {
            bool more = (it + 2 < nit);
            uint4 a2 = a1, b2 = b1;
            if (more) { a2 = ip[2 * it + 4]; b2 = ip[2 * it + 5]; }   // idx for it+2
            u[0].f4 = ((const float4*)(hws + (size_t)a0.x * HD))[fp];
            u[1].f4 = ((const float4*)(hws + (size_t)a0.y * HD))[fp];
            u[2].f4 = ((const float4*)(hws + (size_t)a0.z * HD))[fp];
            u[3].f4 = ((const float4*)(hws + (size_t)a0.w * HD))[fp];
            u[4].f4 = ((const float4*)(hws + (size_t)b0.x * HD))[fp];
            u[5].f4 = ((const float4*)(hws + (size_t)b0.y * HD))[fp];
            u[6].f4 = ((const float4*)(hws + (size_t)b0.z * HD))[fp];
            u[7].f4 = ((const float4*)(hws + (size_t)b0.w * HD))[fp];
#pragma unroll
            for (int q = 0; q < 8; q++)
#pragma unroll
                for (int t = 0; t < 4; t++)
                    hacc[q & 3][t] = __hadd2(hacc[q & 3][t], u[q].h2[t]);
            a0 = a1; b0 = b1;
            a1 = a2; b1 = b2;
        }
    }
    // combine the 4 half2 sets in fp32
#pragma unroll
    for (int t = 0; t < 4; t++) {
        float2 a = __half22float2(hacc[0][t]);
        float2 b = __half22float2(hacc[1][t]);
        float2 c = __half22float2(hacc[2][t]);
        float2 d = __half22float2(hacc[3][t]);
        acc[2 * t]     = (a.x + b.x) + (c.x + d.x);
        acc[2 * t + 1] = (a.y + b.y) + (c.y + d.y);
    }
}

// LN over the 8-features-per-lane layout; xor 1,2,4 stays inside the
// 8-lane group (lane bits 0..2 == fp). Returns relu'd y[8].
__device__ __forceinline__ void ln8(float v[8], int fp,
                                    const float* __restrict__ g,
                                    const float* __restrict__ bb,
                                    float y[8]) {
    float su = 0.0f;
#pragma unroll
    for (int t = 0; t < 8; t++) su += v[t];
    su += __shfl_xor(su, 1, 64); su += __shfl_xor(su, 2, 64); su += __shfl_xor(su, 4, 64);
    float mu = su * (1.0f / HD);
    float q = 0.0f;
#pragma unroll
    for (int t = 0; t < 8; t++) { float d = v[t] - mu; q += d * d; }
    q += __shfl_xor(q, 1, 64); q += __shfl_xor(q, 2, 64); q += __shfl_xor(q, 4, 64);
    float rstd = rsqrtf(q * (1.0f / HD) + 1e-5f);
    float4 ga = ((const float4*)g)[fp * 2], gb = ((const float4*)g)[fp * 2 + 1];
    float4 ba = ((const float4*)bb)[fp * 2], bc = ((const float4*)bb)[fp * 2 + 1];
    float gv[8] = {ga.x, ga.y, ga.z, ga.w, gb.x, gb.y, gb.z, gb.w};
    float bv[8] = {ba.x, ba.y, ba.z, ba.w, bc.x, bc.y, bc.z, bc.w};
#pragma unroll
    for (int t = 0; t < 8; t++) y[t] = fmaxf((v[t] - mu) * rstd * gv[t] + bv[t], 0.0f);
}

// ---------------- layer-1 gather (8 nodes/wave) + bias + LN + ReLU -> h1 fp16 ----------------
__global__ __launch_bounds__(256, 4) void gather_ln(const int* __restrict__ offs,
                                                    const int* __restrict__ pdeg,
                                                    const unsigned int* __restrict__ ssrc,
                                                    const float* __restrict__ di,
                                                    const __half* __restrict__ hws,
                                                    const float* __restrict__ cb,
                                                    const float* __restrict__ g,
                                                    const float* __restrict__ bb,
                                                    __half* __restrict__ out) {
    int wv = threadIdx.x >> 6;
    int lane = threadIdx.x & 63;
    int fp = lane & 7, gg = lane >> 3;
    int node = blockIdx.x * 32 + wv * 8 + gg;   // NN % 32 == 0
    float acc[8];
    gather_node8(offs, pdeg, ssrc, hws, node, fp, acc);
    float4 ca = ((const float4*)cb)[fp * 2], cc = ((const float4*)cb)[fp * 2 + 1];
    float cv[8] = {ca.x, ca.y, ca.z, ca.w, cc.x, cc.y, cc.z, cc.w};
    float dn = di[node];
    float v[8], y[8];
#pragma unroll
    for (int t = 0; t < 8; t++) v[t] = acc[t] * dn + cv[t];
    ln8(v, fp, g, bb, y);
    union U { float4 f4; __half2 h2[4]; } u;
#pragma unroll
    for (int t = 0; t < 4; t++) u.h2[t] = __floats2half2_rn(y[2 * t], y[2 * t + 1]);
    ((float4*)(out + (size_t)node * HD))[fp] = u.f4;   // wave writes 1KB contiguous
}

// ---------------- layer-2 gather (8 nodes/wave) + LN + ReLU + skip + pooled scatter ----------------
// R14: LDS transpose (stride 65) back to 64-lane CONTIGUOUS atomics.
__global__ __launch_bounds__(256, 4) void gather_ln_pool(const int* __restrict__ offs,
                                                         const int* __restrict__ pdeg,
                                                         const unsigned int* __restrict__ ssrc,
                                                         const float* __restrict__ di,
                                                         const __half* __restrict__ hws,
                                                         const float* __restrict__ cb,
                                                         const float* __restrict__ g,
                                                         const float* __restrict__ bb,
                                                         const __half* __restrict__ h1,
                                                         const int* __restrict__ batch,
                                                         float* __restrict__ readout) {
    __shared__ float ls[32][65];
    __shared__ int lb[32];
    int wv = threadIdx.x >> 6;
    int lane = threadIdx.x & 63;
    int fp = lane & 7, gg = lane >> 3;
    int node = blockIdx.x * 32 + wv * 8 + gg;
    float acc[8];
    gather_node8(offs, pdeg, ssrc, hws, node, fp, acc);
    float4 ca = ((const float4*)cb)[fp * 2], cc = ((const float4*)cb)[fp * 2 + 1];
    float cv[8] = {ca.x, ca.y, ca.z, ca.w, cc.x, cc.y, cc.z, cc.w};
    float dn = di[node];
    float v[8], y[8];
#pragma unroll
    for (int t = 0; t < 8; t++) v[t] = acc[t] * dn + cv[t];
    ln8(v, fp, g, bb, y);
    // skip connection: s = relu(ln(conv2)) + h1
    union U { float4 f4; __half2 h2[4]; } u;
    u.f4 = ((const float4*)(h1 + (size_t)node * HD))[fp];
    int row = wv * 8 + gg;
#pragma unroll
    for (int t = 0; t < 4; t++) {
        float2 p = __half22float2(u.h2[t]);
        ls[row][fp * 8 + 2 * t]     = y[2 * t] + p.x;
        ls[row][fp * 8 + 2 * t + 1] = y[2 * t + 1] + p.y;
    }
    if (fp == 0) lb[row] = batch[node];
    // rows of this wave are wave-private: per-wave DS ordering suffices, no __syncthreads
    int r0 = wv * 8;
    int bu = lb[r0];
    bool uni = true;
#pragma unroll
    for (int r = 1; r < 8; r++) uni = uni && (lb[r0 + r] == bu);
    int f = lane;
    if (uni) {
        float s2 = 0.0f;
#pragma unroll
        for (int r = 0; r < 8; r++) s2 += ls[r0 + r][f];
        atomicAdd(&readout[(size_t)bu * HD + f], s2);   // 64-lane contiguous
    } else {
        // batch sorted within the wave's 8 rows: merge equal runs
        float s2 = ls[r0][f];
        int bprev = lb[r0];
#pragma unroll
        for (int r = 1; r < 8; r++) {
            int bn = lb[r0 + r];
            if (bn == bprev) {
                s2 += ls[r0 + r][f];
            } else {
                atomicAdd(&readout[(size_t)bprev * HD + f], s2);
                s2 = ls[r0 + r][f];
                bprev = bn;
            }
        }
        atomicAdd(&readout[(size_t)bprev * HD + f], s2);
    }
}

// ---------------- final: out = readout @ post_w + post_b  [G,64]@[64,40] ----------------
__global__ __launch_bounds__(256) void out_gemm(const float* __restrict__ r,
                                                const float* __restrict__ w,
                                                const float* __restrict__ b,
                                                float* __restrict__ out) {
    __shared__ float lw[HD * CO];
    for (int i = threadIdx.x; i < HD * CO; i += 256) lw[i] = w[i];
    __syncthreads();
    int grp = blockIdx.x * 4 + (threadIdx.x >> 6);
    int c = threadIdx.x & 63;
    if (grp >= NG || c >= CO) return;
    const float* rr = r + (size_t)grp * HD;
    float acc = b[c];
#pragma unroll 8
    for (int k = 0; k < HD; k++) acc = fmaf(rr[k], lw[k * CO + c], acc);
    out[(size_t)grp * CO + c] = acc;
}

extern "C" void kernel_launch(void* const* d_in, const int* in_sizes, int n_in,
                              void* d_out, int out_size, void* d_ws, size_t ws_size,
                              hipStream_t stream) {
    const float* x      = (const float*)d_in[0];
    const int*   ei     = (const int*)d_in[1];
    const int*   batch  = (const int*)d_in[2];
    const float* pre_w  = (const float*)d_in[3];
    const float* pre_b  = (const float*)d_in[4];
    const float* c1_w   = (const float*)d_in[5];
    const float* c1_b   = (const float*)d_in[6];
    const float* n1_g   = (const float*)d_in[7];
    const float* n1_b   = (const float*)d_in[8];
    const float* c2_w   = (const float*)d_in[9];
    const float* c2_b   = (const float*)d_in[10];
    const float* n2_g   = (const float*)d_in[11];
    const float* n2_b   = (const float*)d_in[12];
    const float* post_w = (const float*)d_in[13];
    const float* post_b = (const float*)d_in[14];

    const int* src = ei;
    const int* dst = ei + NE;

    char* p = (char*)d_ws;
    int*          scur    = (int*)p;          p += (size_t)NSB * 16 * 4;
    int*          offs    = (int*)p;          p += (size_t)NN * 4;
    int*          degn    = (int*)p;          p += (size_t)NN * 4;
    float*        di      = (float*)p;        p += (size_t)NN * 4;
    _Float16*     wth     = (_Float16*)p;     p += (size_t)FIN * HD * 2;   // W_eff^T fp16
    _Float16*     wt2h    = (_Float16*)p;     p += (size_t)HD * HD * 2;    // c2_w^T fp16
    float*        beff    = (float*)p;        p += 256;
    unsigned int* stmp    = (unsigned int*)p; p += (size_t)NSB * SCAP * 4;
    unsigned int* ssrc    = (unsigned int*)p; p += (size_t)NSB * GCAP * 4;
    float*        readout = (float*)p;        p += (size_t)NG * HD * 4;
    __half*       hws     = (__half*)p;       p += (size_t)(NN + 8) * HD * 2;  // +dummy row
    __half*       h1      = (__half*)p;       p += (size_t)NN * HD * 2;

    // setup: cursors, readout zero, dummy hws row zero
    setup_kernel<<<(NG * HD + 255) / 256, 256, 0, stream>>>(scur, readout,
                                                            (unsigned int*)(hws + (size_t)NN * HD));

    // two-level CSR build: super-bucket scatter -> per-group counting sort
    scatter_super<<<NSCAT, 1024, 0, stream>>>(src, dst, scur, stmp);
    group_sort<<<NSB, 1024, 0, stream>>>(scur, stmp, ssrc, offs, degn, di);

    // Folded pre-MLP weights + fp16 transposed copies (one-shot)
    weff_kernel<<<49, 256, 0, stream>>>(pre_w, pre_b, c1_w, c2_w, wth, beff, wt2h);

    // layer 1
    gemm1_mfma<<<(NN + 63) / 64, 256, 0, stream>>>(x, wth, beff, di, hws);
    gather_ln<<<NN / 32, 256, 0, stream>>>(offs, degn, ssrc, di, hws, c1_b, n1_g, n1_b, h1);

    // layer 2
    conv_gemm_mfma<<<(NN + 63) / 64, 256, 0, stream>>>(h1, wt2h, di, hws);
    gather_ln_pool<<<NN / 32, 256, 0, stream>>>(offs, degn, ssrc, di, hws, c2_b, n2_g, n2_b, h1, batch, readout);

    out_gemm<<<(NG + 3) / 4, 256, 0, stream>>>(readout, post_w, post_b, (float*)d_out);
}